// Round 1
// baseline (681.921 us; speedup 1.0000x reference)
//
#include <hip/hip_runtime.h>
#include <hip/hip_bf16.h>

typedef __attribute__((ext_vector_type(8))) short bf16x8;
typedef __attribute__((ext_vector_type(4))) float f32x4;
typedef __attribute__((ext_vector_type(4))) short s16x4;
typedef unsigned short ushort_t;

__device__ __forceinline__ unsigned short f2bf(float f) {
    unsigned int u = __float_as_uint(f);
    u = (u + 0x7FFFu + ((u >> 16) & 1u)) >> 16;   // RNE
    return (unsigned short)u;
}
__device__ __forceinline__ float fast_sigmoid(float x) {
    return 1.0f / (1.0f + __expf(-x));
}
__device__ __forceinline__ float fast_tanh(float x) {
    x = fminf(fmaxf(x, -15.0f), 15.0f);
    float e = __expf(2.0f * x);
    return (e - 1.0f) / (e + 1.0f);
}
__device__ __forceinline__ f32x4 mfma16(bf16x8 a, bf16x8 b, f32x4 c) {
    return __builtin_amdgcn_mfma_f32_16x16x32_bf16(a, b, c, 0, 0, 0);
}

// ---- weight fp32 -> bf16 conversion (runs every launch; ws is re-poisoned) ----
// layout in ws (bf16 elems): W1 128x512 @0, W2 64x128 @65536, W3 128x64 @73728,
// WIH 512x640 @81920, FCW 128x128 @409600. total 425984 elems = 851968 B.
__global__ void convert_w_kernel(const float* __restrict__ w1, const float* __restrict__ w2,
                                 const float* __restrict__ w3, const float* __restrict__ wih,
                                 const float* __restrict__ fcw, ushort_t* __restrict__ outw) {
    int i = blockIdx.x * 256 + threadIdx.x;   // grid covers exactly 425984
    float v;
    if (i < 65536)       v = w1[i];
    else if (i < 73728)  v = w2[i - 65536];
    else if (i < 81920)  v = w3[i - 73728];
    else if (i < 409600) v = wih[i - 81920];
    else                 v = fcw[i - 409600];
    outw[i] = f2bf(v);
}

#define XS_LD 520   // 512 + 8 pad (bank offset 4/row, 2-way max -> free)
#define D1_LD 136   // 128 + 8
#define D2_LD 72    // 64 + 8
#define D3_LD 136
#define HS_LD 136

// M=32 rows per block, 512 threads (8 waves). Wave w owns a 16-wide N slice.
__global__ __launch_bounds__(512, 4) void fused_mlp_lstm_kernel(
    const float* __restrict__ x,
    const float* __restrict__ b1, const float* __restrict__ b2, const float* __restrict__ b3,
    const float* __restrict__ b_ih, const float* __restrict__ b_hh,
    const float* __restrict__ fc_b,
    const ushort_t* __restrict__ wbf,
    float* __restrict__ out)
{
    __shared__ ushort_t sm[32 * (XS_LD + D1_LD + D2_LD + D3_LD + HS_LD)]; // 64000 B
    ushort_t* xs  = sm;
    ushort_t* d1s = xs  + 32 * XS_LD;
    ushort_t* d2s = d1s + 32 * D1_LD;
    ushort_t* d3s = d2s + 32 * D2_LD;
    ushort_t* hs  = d3s + 32 * D3_LD;

    const ushort_t* W1  = wbf;            // (128,512)
    const ushort_t* W2  = wbf + 65536;    // (64,128)
    const ushort_t* W3  = wbf + 73728;    // (128,64)
    const ushort_t* WIH = wbf + 81920;    // (512,640)
    const ushort_t* FCW = wbf + 409600;   // (128,128)

    const int t  = threadIdx.x;
    const int w  = t >> 6;        // wave 0..7
    const int l  = t & 63;
    const int q  = l >> 4;        // quad 0..3
    const int lm = l & 15;
    const int ko = q * 8;         // k-offset within a 32-wide K step
    const int n0 = w * 16;        // this wave's N slice
    const long rowBase = (long)blockIdx.x * 32;

    // ---- stage x tile (32x512 fp32) -> bf16 LDS, coalesced float4 ----
    {
        const float4* xv = (const float4*)(x + rowBase * 512);
        #pragma unroll
        for (int i = 0; i < 8; ++i) {
            int idx = t + i * 512;       // 0..4095
            int row = idx >> 7;
            int c4  = idx & 127;
            float4 v = xv[row * 128 + c4];
            s16x4 pk;
            pk.x = (short)f2bf(v.x); pk.y = (short)f2bf(v.y);
            pk.z = (short)f2bf(v.z); pk.w = (short)f2bf(v.w);
            *(s16x4*)(xs + row * XS_LD + c4 * 4) = pk;
        }
    }
    __syncthreads();

    // ---- phase 1: d1 = relu(x @ W1^T + b1)  M=32 N=128 K=512 ----
    {
        f32x4 a0 = {0,0,0,0}, a1 = {0,0,0,0};
        #pragma unroll
        for (int kk = 0; kk < 16; ++kk) {
            int k0 = kk * 32 + ko;
            bf16x8 fa0 = *(const bf16x8*)(xs + lm * XS_LD + k0);
            bf16x8 fa1 = *(const bf16x8*)(xs + (16 + lm) * XS_LD + k0);
            bf16x8 fb  = *(const bf16x8*)(W1 + (n0 + lm) * 512 + k0);
            a0 = mfma16(fa0, fb, a0);
            a1 = mfma16(fa1, fb, a1);
        }
        float bv = b1[n0 + lm];
        #pragma unroll
        for (int r = 0; r < 4; ++r) {
            d1s[(q * 4 + r) * D1_LD + n0 + lm]      = f2bf(fmaxf(a0[r] + bv, 0.0f));
            d1s[(16 + q * 4 + r) * D1_LD + n0 + lm] = f2bf(fmaxf(a1[r] + bv, 0.0f));
        }
    }
    __syncthreads();

    // ---- phase 2: d2 = relu(d1 @ W2^T + b2)  M=32 N=64 K=128 (waves 0-3) ----
    if (w < 4) {
        f32x4 a0 = {0,0,0,0}, a1 = {0,0,0,0};
        #pragma unroll
        for (int kk = 0; kk < 4; ++kk) {
            int k0 = kk * 32 + ko;
            bf16x8 fa0 = *(const bf16x8*)(d1s + lm * D1_LD + k0);
            bf16x8 fa1 = *(const bf16x8*)(d1s + (16 + lm) * D1_LD + k0);
            bf16x8 fb  = *(const bf16x8*)(W2 + (n0 + lm) * 128 + k0);
            a0 = mfma16(fa0, fb, a0);
            a1 = mfma16(fa1, fb, a1);
        }
        float bv = b2[n0 + lm];
        #pragma unroll
        for (int r = 0; r < 4; ++r) {
            d2s[(q * 4 + r) * D2_LD + n0 + lm]      = f2bf(fmaxf(a0[r] + bv, 0.0f));
            d2s[(16 + q * 4 + r) * D2_LD + n0 + lm] = f2bf(fmaxf(a1[r] + bv, 0.0f));
        }
    }
    __syncthreads();

    // ---- phase 3: d3 = d2 @ W3^T + b3  M=32 N=128 K=64 (no relu) ----
    {
        f32x4 a0 = {0,0,0,0}, a1 = {0,0,0,0};
        #pragma unroll
        for (int kk = 0; kk < 2; ++kk) {
            int k0 = kk * 32 + ko;
            bf16x8 fa0 = *(const bf16x8*)(d2s + lm * D2_LD + k0);
            bf16x8 fa1 = *(const bf16x8*)(d2s + (16 + lm) * D2_LD + k0);
            bf16x8 fb  = *(const bf16x8*)(W3 + (n0 + lm) * 64 + k0);
            a0 = mfma16(fa0, fb, a0);
            a1 = mfma16(fa1, fb, a1);
        }
        float bv = b3[n0 + lm];
        #pragma unroll
        for (int r = 0; r < 4; ++r) {
            d3s[(q * 4 + r) * D3_LD + n0 + lm]      = f2bf(a0[r] + bv);
            d3s[(16 + q * 4 + r) * D3_LD + n0 + lm] = f2bf(a1[r] + bv);
        }
    }
    // NOTE: no barrier yet — gates part A only needs xs. Barrier before part B.

    // ---- phase 4: gates (i,g,o only; f is dead). wave w owns cols [16w,16w+16)
    //      of each of i/g/o so the LSTM elementwise stays in registers. ----
    f32x4 aI0 = {0,0,0,0}, aI1 = {0,0,0,0};
    f32x4 aG0 = {0,0,0,0}, aG1 = {0,0,0,0};
    f32x4 aO0 = {0,0,0,0}, aO1 = {0,0,0,0};
    const int rI = n0;          // W_ih rows for i-gate
    const int rG = 256 + n0;    // g-gate
    const int rO = 384 + n0;    // o-gate
    #pragma unroll
    for (int kk = 0; kk < 16; ++kk) {        // K part A: x (512)
        int k0 = kk * 32 + ko;
        bf16x8 fa0 = *(const bf16x8*)(xs + lm * XS_LD + k0);
        bf16x8 fa1 = *(const bf16x8*)(xs + (16 + lm) * XS_LD + k0);
        bf16x8 bi  = *(const bf16x8*)(WIH + (rI + lm) * 640 + k0);
        bf16x8 bg  = *(const bf16x8*)(WIH + (rG + lm) * 640 + k0);
        bf16x8 bo  = *(const bf16x8*)(WIH + (rO + lm) * 640 + k0);
        aI0 = mfma16(fa0, bi, aI0); aI1 = mfma16(fa1, bi, aI1);
        aG0 = mfma16(fa0, bg, aG0); aG1 = mfma16(fa1, bg, aG1);
        aO0 = mfma16(fa0, bo, aO0); aO1 = mfma16(fa1, bo, aO1);
    }
    __syncthreads();   // d3s now safe to read
    #pragma unroll
    for (int kk = 0; kk < 4; ++kk) {         // K part B: d3 (128) = WIH cols 512..639
        int k0 = kk * 32 + ko;
        bf16x8 fa0 = *(const bf16x8*)(d3s + lm * D3_LD + k0);
        bf16x8 fa1 = *(const bf16x8*)(d3s + (16 + lm) * D3_LD + k0);
        bf16x8 bi  = *(const bf16x8*)(WIH + (rI + lm) * 640 + 512 + k0);
        bf16x8 bg  = *(const bf16x8*)(WIH + (rG + lm) * 640 + 512 + k0);
        bf16x8 bo  = *(const bf16x8*)(WIH + (rO + lm) * 640 + 512 + k0);
        aI0 = mfma16(fa0, bi, aI0); aI1 = mfma16(fa1, bi, aI1);
        aG0 = mfma16(fa0, bg, aG0); aG1 = mfma16(fa1, bg, aG1);
        aO0 = mfma16(fa0, bo, aO0); aO1 = mfma16(fa1, bo, aO1);
    }
    {
        float biasI = b_ih[rI + lm] + b_hh[rI + lm];
        float biasG = b_ih[rG + lm] + b_hh[rG + lm];
        float biasO = b_ih[rO + lm] + b_hh[rO + lm];
        #pragma unroll
        for (int r = 0; r < 4; ++r) {
            float c0 = fast_sigmoid(aI0[r] + biasI) * fast_tanh(aG0[r] + biasG);
            float h0 = fast_sigmoid(aO0[r] + biasO) * fast_tanh(c0);
            float c1 = fast_sigmoid(aI1[r] + biasI) * fast_tanh(aG1[r] + biasG);
            float h1 = fast_sigmoid(aO1[r] + biasO) * fast_tanh(c1);
            hs[(q * 4 + r) * HS_LD + n0 + lm]      = f2bf(h0);
            hs[(16 + q * 4 + r) * HS_LD + n0 + lm] = f2bf(h1);
        }
    }
    __syncthreads();

    // ---- phase 5: out = h @ fc_w^T + fc_b  M=32 N=128 K=128 (attention is identity) ----
    {
        f32x4 a0 = {0,0,0,0}, a1 = {0,0,0,0};
        #pragma unroll
        for (int kk = 0; kk < 4; ++kk) {
            int k0 = kk * 32 + ko;
            bf16x8 fa0 = *(const bf16x8*)(hs + lm * HS_LD + k0);
            bf16x8 fa1 = *(const bf16x8*)(hs + (16 + lm) * HS_LD + k0);
            bf16x8 fb  = *(const bf16x8*)(FCW + (n0 + lm) * 128 + k0);
            a0 = mfma16(fa0, fb, a0);
            a1 = mfma16(fa1, fb, a1);
        }
        float bv = fc_b[n0 + lm];
        #pragma unroll
        for (int r = 0; r < 4; ++r) {
            out[(rowBase + q * 4 + r) * 128 + n0 + lm]      = a0[r] + bv;
            out[(rowBase + 16 + q * 4 + r) * 128 + n0 + lm] = a1[r] + bv;
        }
    }
}

extern "C" void kernel_launch(void* const* d_in, const int* in_sizes, int n_in,
                              void* d_out, int out_size, void* d_ws, size_t ws_size,
                              hipStream_t stream) {
    const float* x    = (const float*)d_in[0];
    const float* w1   = (const float*)d_in[1];
    const float* b1   = (const float*)d_in[2];
    const float* w2   = (const float*)d_in[3];
    const float* b2   = (const float*)d_in[4];
    const float* w3   = (const float*)d_in[5];
    const float* b3   = (const float*)d_in[6];
    const float* wih  = (const float*)d_in[7];
    // d_in[8] = W_hh (dead: h_prev == 0), d_in[11]/[12] = attn (dead: seq len 1)
    const float* b_ih = (const float*)d_in[9];
    const float* b_hh = (const float*)d_in[10];
    const float* fcw  = (const float*)d_in[13];
    const float* fcb  = (const float*)d_in[14];

    ushort_t* wbf = (ushort_t*)d_ws;   // 851968 B of bf16 weights
    float* out = (float*)d_out;

    convert_w_kernel<<<1664, 256, 0, stream>>>(w1, w2, w3, wih, fcw, wbf);
    fused_mlp_lstm_kernel<<<131072 / 32, 512, 0, stream>>>(
        x, b1, b2, b3, b_ih, b_hh, fcb, wbf, out);
}

// Round 2
// 577.286 us; speedup vs baseline: 1.1813x; 1.1813x over previous
//
#include <hip/hip_runtime.h>
#include <hip/hip_bf16.h>

typedef __attribute__((ext_vector_type(8))) short bf16x8;
typedef __attribute__((ext_vector_type(4))) float f32x4;
typedef __attribute__((ext_vector_type(4))) short s16x4;
typedef unsigned short ushort_t;

__device__ __forceinline__ unsigned short f2bf(float f) {
    unsigned int u = __float_as_uint(f);
    u = (u + 0x7FFFu + ((u >> 16) & 1u)) >> 16;   // RNE
    return (unsigned short)u;
}
__device__ __forceinline__ float fast_sigmoid(float x) {
    return 1.0f / (1.0f + __expf(-x));
}
__device__ __forceinline__ float fast_tanh(float x) {
    x = fminf(fmaxf(x, -15.0f), 15.0f);
    float e = __expf(2.0f * x);
    return (e - 1.0f) / (e + 1.0f);
}
__device__ __forceinline__ f32x4 mfma16(bf16x8 a, bf16x8 b, f32x4 c) {
    return __builtin_amdgcn_mfma_f32_16x16x32_bf16(a, b, c, 0, 0, 0);
}

// ---- weight fp32 -> bf16 conversion (runs every launch; ws is re-poisoned) ----
// layout in ws (bf16 elems): W1 128x512 @0, W2 64x128 @65536, W3 128x64 @73728,
// WIH 512x640 @81920, FCW 128x128 @409600. total 425984 elems = 851968 B.
__global__ void convert_w_kernel(const float* __restrict__ w1, const float* __restrict__ w2,
                                 const float* __restrict__ w3, const float* __restrict__ wih,
                                 const float* __restrict__ fcw, ushort_t* __restrict__ outw) {
    int i = blockIdx.x * 256 + threadIdx.x;   // grid covers exactly 425984
    float v;
    if (i < 65536)       v = w1[i];
    else if (i < 73728)  v = w2[i - 65536];
    else if (i < 81920)  v = w3[i - 73728];
    else if (i < 409600) v = wih[i - 81920];
    else                 v = fcw[i - 409600];
    outw[i] = f2bf(v);
}

#define XS_LD 520   // 512 + 8 pad; stride%32dw = 4 -> 8 lanes per 4-bank group = throughput-ideal
#define D1_LD 136
#define D2_LD 72
#define D3_LD 136
#define HS_LD 136
// M=64: LDS = 64*(520+136+72+136+136)*2 = 128000 B -> 1 block/CU, 8 waves.

// M=64 rows per block, 512 threads (8 waves). Wave w owns a 16-wide N slice,
// all 64 rows (4 A-subtiles). All phase-B weight fragments preloaded into
// registers (unrolled arrays) so 16-24 L2 loads are in flight per wave.
__global__ __launch_bounds__(512, 2) void fused_mlp_lstm_kernel(
    const float* __restrict__ x,
    const float* __restrict__ b1, const float* __restrict__ b2, const float* __restrict__ b3,
    const float* __restrict__ b_ih, const float* __restrict__ b_hh,
    const float* __restrict__ fc_b,
    const ushort_t* __restrict__ wbf,
    float* __restrict__ out)
{
    __shared__ ushort_t sm[64 * (XS_LD + D1_LD + D2_LD + D3_LD + HS_LD)];
    ushort_t* xs  = sm;
    ushort_t* d1s = xs  + 64 * XS_LD;
    ushort_t* d2s = d1s + 64 * D1_LD;
    ushort_t* d3s = d2s + 64 * D2_LD;
    ushort_t* hs  = d3s + 64 * D3_LD;

    const ushort_t* W1  = wbf;            // (128,512)
    const ushort_t* W2  = wbf + 65536;    // (64,128)
    const ushort_t* W3  = wbf + 73728;    // (128,64)
    const ushort_t* WIH = wbf + 81920;    // (512,640)
    const ushort_t* FCW = wbf + 409600;   // (128,128)

    const int t  = threadIdx.x;
    const int w  = t >> 6;        // wave 0..7
    const int l  = t & 63;
    const int q  = l >> 4;        // quad 0..3
    const int lm = l & 15;
    const int ko = q * 8;
    const int n0 = w * 16;        // this wave's N slice (phases 1,3,4,5)
    const long rowBase = (long)blockIdx.x * 64;

    // ---- phase1 B preload: W1 rows n0..n0+15, all 16 K-steps (64 VGPRs) ----
    bf16x8 bw1[16];
    #pragma unroll
    for (int kk = 0; kk < 16; ++kk)
        bw1[kk] = *(const bf16x8*)(W1 + (n0 + lm) * 512 + kk * 32 + ko);

    // ---- stage-a: x cols [0,256) -> bf16 LDS ----
    const float4* xv = (const float4*)(x + rowBase * 512);
    #pragma unroll
    for (int i = 0; i < 8; ++i) {
        int u = t + i * 512;              // 0..4095
        int row = u >> 6, c4 = u & 63;    // 64 float4s per half-row
        float4 v = xv[row * 128 + c4];
        s16x4 pk;
        pk.x = (short)f2bf(v.x); pk.y = (short)f2bf(v.y);
        pk.z = (short)f2bf(v.z); pk.w = (short)f2bf(v.w);
        *(s16x4*)(xs + row * XS_LD + c4 * 4) = pk;
    }
    __syncthreads();

    // ---- stage-b loads (cols [256,512)) into regs; overlap with phase1a ----
    float4 vb[8];
    #pragma unroll
    for (int i = 0; i < 8; ++i) {
        int u = t + i * 512;
        vb[i] = xv[(u >> 6) * 128 + 64 + (u & 63)];
    }

    // ---- phase1a: kk 0..7 (uses xs cols < 256) ----
    f32x4 a1[4] = {{0,0,0,0},{0,0,0,0},{0,0,0,0},{0,0,0,0}};
    #pragma unroll
    for (int kk = 0; kk < 8; ++kk) {
        #pragma unroll
        for (int s = 0; s < 4; ++s) {
            bf16x8 fa = *(const bf16x8*)(xs + (s * 16 + lm) * XS_LD + kk * 32 + ko);
            a1[s] = mfma16(fa, bw1[kk], a1[s]);
        }
    }

    // ---- stage-b writes (cols >= 256: disjoint from phase1a reads, no barrier yet) ----
    #pragma unroll
    for (int i = 0; i < 8; ++i) {
        int u = t + i * 512;
        int row = u >> 6, c4 = u & 63;
        s16x4 pk;
        pk.x = (short)f2bf(vb[i].x); pk.y = (short)f2bf(vb[i].y);
        pk.z = (short)f2bf(vb[i].z); pk.w = (short)f2bf(vb[i].w);
        *(s16x4*)(xs + row * XS_LD + (64 + c4) * 4) = pk;
    }
    __syncthreads();

    // ---- phase1b: kk 8..15, bias+relu, store d1s ----
    #pragma unroll
    for (int kk = 8; kk < 16; ++kk) {
        #pragma unroll
        for (int s = 0; s < 4; ++s) {
            bf16x8 fa = *(const bf16x8*)(xs + (s * 16 + lm) * XS_LD + kk * 32 + ko);
            a1[s] = mfma16(fa, bw1[kk], a1[s]);
        }
    }
    {
        float bv = b1[n0 + lm];
        #pragma unroll
        for (int s = 0; s < 4; ++s)
            #pragma unroll
            for (int r = 0; r < 4; ++r)
                d1s[(s * 16 + q * 4 + r) * D1_LD + n0 + lm] = f2bf(fmaxf(a1[s][r] + bv, 0.0f));
    }

    // ---- phase2 B preload (global; safe before barrier) ----
    const int w4 = w & 3, half = w >> 2;   // wave -> (col slice, row half) for N=64 phase
    const int n2 = w4 * 16;
    bf16x8 bw2[4];
    #pragma unroll
    for (int kk = 0; kk < 4; ++kk)
        bw2[kk] = *(const bf16x8*)(W2 + (n2 + lm) * 128 + kk * 32 + ko);
    __syncthreads();   // d1s ready

    // ---- phase2: d2 = relu(d1 @ W2^T + b2)  M=64 N=64 K=128 ----
    {
        f32x4 a2[2] = {{0,0,0,0},{0,0,0,0}};
        #pragma unroll
        for (int kk = 0; kk < 4; ++kk) {
            #pragma unroll
            for (int s = 0; s < 2; ++s) {
                bf16x8 fa = *(const bf16x8*)(d1s + (half * 32 + s * 16 + lm) * D1_LD + kk * 32 + ko);
                a2[s] = mfma16(fa, bw2[kk], a2[s]);
            }
        }
        float bv = b2[n2 + lm];
        #pragma unroll
        for (int s = 0; s < 2; ++s)
            #pragma unroll
            for (int r = 0; r < 4; ++r)
                d2s[(half * 32 + s * 16 + q * 4 + r) * D2_LD + n2 + lm] = f2bf(fmaxf(a2[s][r] + bv, 0.0f));
    }

    // ---- phase3 + phase4-chunk0 B preloads (global; before barrier) ----
    const int rI = n0, rG = 256 + n0, rO = 384 + n0;
    bf16x8 bw3[2];
    #pragma unroll
    for (int kk = 0; kk < 2; ++kk)
        bw3[kk] = *(const bf16x8*)(W3 + (n0 + lm) * 64 + kk * 32 + ko);
    bf16x8 bi0[8], bg0[8], bo0[8];
    #pragma unroll
    for (int j = 0; j < 8; ++j) {
        bi0[j] = *(const bf16x8*)(WIH + (rI + lm) * 640 + j * 32 + ko);
        bg0[j] = *(const bf16x8*)(WIH + (rG + lm) * 640 + j * 32 + ko);
        bo0[j] = *(const bf16x8*)(WIH + (rO + lm) * 640 + j * 32 + ko);
    }
    __syncthreads();   // d2s ready

    // ---- phase3: d3 = d2 @ W3^T + b3  (no relu) ----
    {
        f32x4 a3[4] = {{0,0,0,0},{0,0,0,0},{0,0,0,0},{0,0,0,0}};
        #pragma unroll
        for (int kk = 0; kk < 2; ++kk) {
            #pragma unroll
            for (int s = 0; s < 4; ++s) {
                bf16x8 fa = *(const bf16x8*)(d2s + (s * 16 + lm) * D2_LD + kk * 32 + ko);
                a3[s] = mfma16(fa, bw3[kk], a3[s]);
            }
        }
        float bv = b3[n0 + lm];
        #pragma unroll
        for (int s = 0; s < 4; ++s)
            #pragma unroll
            for (int r = 0; r < 4; ++r)
                d3s[(s * 16 + q * 4 + r) * D3_LD + n0 + lm] = f2bf(a3[s][r] + bv);
    }
    // no barrier: phase4 part A reads only xs (stable)

    // ---- phase4 part A: gates vs x, kk 0..15 in 2 register-preloaded chunks ----
    f32x4 aI[4] = {{0,0,0,0},{0,0,0,0},{0,0,0,0},{0,0,0,0}};
    f32x4 aG[4] = {{0,0,0,0},{0,0,0,0},{0,0,0,0},{0,0,0,0}};
    f32x4 aO[4] = {{0,0,0,0},{0,0,0,0},{0,0,0,0},{0,0,0,0}};
    #pragma unroll
    for (int j = 0; j < 8; ++j) {
        bf16x8 fa[4];
        #pragma unroll
        for (int s = 0; s < 4; ++s)
            fa[s] = *(const bf16x8*)(xs + (s * 16 + lm) * XS_LD + j * 32 + ko);
        #pragma unroll
        for (int s = 0; s < 4; ++s) {
            aI[s] = mfma16(fa[s], bi0[j], aI[s]);
            aG[s] = mfma16(fa[s], bg0[j], aG[s]);
            aO[s] = mfma16(fa[s], bo0[j], aO[s]);
        }
    }
    {
        bf16x8 bi1[8], bg1[8], bo1[8];
        #pragma unroll
        for (int j = 0; j < 8; ++j) {
            bi1[j] = *(const bf16x8*)(WIH + (rI + lm) * 640 + (8 + j) * 32 + ko);
            bg1[j] = *(const bf16x8*)(WIH + (rG + lm) * 640 + (8 + j) * 32 + ko);
            bo1[j] = *(const bf16x8*)(WIH + (rO + lm) * 640 + (8 + j) * 32 + ko);
        }
        #pragma unroll
        for (int j = 0; j < 8; ++j) {
            bf16x8 fa[4];
            #pragma unroll
            for (int s = 0; s < 4; ++s)
                fa[s] = *(const bf16x8*)(xs + (s * 16 + lm) * XS_LD + (8 + j) * 32 + ko);
            #pragma unroll
            for (int s = 0; s < 4; ++s) {
                aI[s] = mfma16(fa[s], bi1[j], aI[s]);
                aG[s] = mfma16(fa[s], bg1[j], aG[s]);
                aO[s] = mfma16(fa[s], bo1[j], aO[s]);
            }
        }
    }
    // ---- phase4 part B preload (WIH cols 512..639) before d3s barrier ----
    {
        bf16x8 biB[4], bgB[4], boB[4];
        #pragma unroll
        for (int j = 0; j < 4; ++j) {
            biB[j] = *(const bf16x8*)(WIH + (rI + lm) * 640 + 512 + j * 32 + ko);
            bgB[j] = *(const bf16x8*)(WIH + (rG + lm) * 640 + 512 + j * 32 + ko);
            boB[j] = *(const bf16x8*)(WIH + (rO + lm) * 640 + 512 + j * 32 + ko);
        }
        __syncthreads();   // d3s ready
        #pragma unroll
        for (int j = 0; j < 4; ++j) {
            bf16x8 fa[4];
            #pragma unroll
            for (int s = 0; s < 4; ++s)
                fa[s] = *(const bf16x8*)(d3s + (s * 16 + lm) * D3_LD + j * 32 + ko);
            #pragma unroll
            for (int s = 0; s < 4; ++s) {
                aI[s] = mfma16(fa[s], biB[j], aI[s]);
                aG[s] = mfma16(fa[s], bgB[j], aG[s]);
                aO[s] = mfma16(fa[s], boB[j], aO[s]);
            }
        }
    }
    // ---- LSTM elementwise (f-gate dead, h == ctx since seq=1) ----
    {
        float biasI = b_ih[rI + lm] + b_hh[rI + lm];
        float biasG = b_ih[rG + lm] + b_hh[rG + lm];
        float biasO = b_ih[rO + lm] + b_hh[rO + lm];
        #pragma unroll
        for (int s = 0; s < 4; ++s)
            #pragma unroll
            for (int r = 0; r < 4; ++r) {
                float c = fast_sigmoid(aI[s][r] + biasI) * fast_tanh(aG[s][r] + biasG);
                float h = fast_sigmoid(aO[s][r] + biasO) * fast_tanh(c);
                hs[(s * 16 + q * 4 + r) * HS_LD + n0 + lm] = f2bf(h);
            }
    }
    // ---- phase5 B preload before hs barrier ----
    bf16x8 bw5[4];
    #pragma unroll
    for (int kk = 0; kk < 4; ++kk)
        bw5[kk] = *(const bf16x8*)(FCW + (n0 + lm) * 128 + kk * 32 + ko);
    __syncthreads();   // hs ready

    // ---- phase5: out = h @ fc_w^T + fc_b ----
    {
        f32x4 a5[4] = {{0,0,0,0},{0,0,0,0},{0,0,0,0},{0,0,0,0}};
        #pragma unroll
        for (int kk = 0; kk < 4; ++kk) {
            #pragma unroll
            for (int s = 0; s < 4; ++s) {
                bf16x8 fa = *(const bf16x8*)(hs + (s * 16 + lm) * HS_LD + kk * 32 + ko);
                a5[s] = mfma16(fa, bw5[kk], a5[s]);
            }
        }
        float bv = fc_b[n0 + lm];
        #pragma unroll
        for (int s = 0; s < 4; ++s)
            #pragma unroll
            for (int r = 0; r < 4; ++r)
                out[(rowBase + s * 16 + q * 4 + r) * 128 + n0 + lm] = a5[s][r] + bv;
    }
}

extern "C" void kernel_launch(void* const* d_in, const int* in_sizes, int n_in,
                              void* d_out, int out_size, void* d_ws, size_t ws_size,
                              hipStream_t stream) {
    const float* x    = (const float*)d_in[0];
    const float* w1   = (const float*)d_in[1];
    const float* b1   = (const float*)d_in[2];
    const float* w2   = (const float*)d_in[3];
    const float* b2   = (const float*)d_in[4];
    const float* w3   = (const float*)d_in[5];
    const float* b3   = (const float*)d_in[6];
    const float* wih  = (const float*)d_in[7];
    // d_in[8] = W_hh (dead: h_prev == 0), d_in[11]/[12] = attn (dead: seq len 1)
    const float* b_ih = (const float*)d_in[9];
    const float* b_hh = (const float*)d_in[10];
    const float* fcw  = (const float*)d_in[13];
    const float* fcb  = (const float*)d_in[14];

    ushort_t* wbf = (ushort_t*)d_ws;   // 851968 B of bf16 weights
    float* out = (float*)d_out;

    convert_w_kernel<<<1664, 256, 0, stream>>>(w1, w2, w3, wih, fcw, wbf);
    fused_mlp_lstm_kernel<<<131072 / 64, 512, 0, stream>>>(
        x, b1, b2, b3, b_ih, b_hh, fcb, wbf, out);
}